// Round 4
// baseline (371.638 us; speedup 1.0000x reference)
//
#include <hip/hip_runtime.h>

typedef unsigned short u16;
typedef __attribute__((ext_vector_type(8))) short short8;
typedef __attribute__((ext_vector_type(16))) float f32x16;

#define DIM 2048
#define NROWS 8192
#define SLOPE 0.001f
#define LN_EPS 1e-5f

#define LN_BLOCKS 4096              // 16384 rows, 4 rows (waves) per block
#define WT_BLOCKS 2048              // 2 towers * (2048/64)^2 tiles

// GEMM geometry (m201-faithful): 256x256 C tile, 512 thr = 8 waves (2x4),
// 128x64 per wave (acc[4][2] of 32x32), BK=64. LDS: A 3-buf + B 2-buf = 160 KiB.
#define BM 256
#define BN 256
#define BK 64
#define NT (DIM / BK)               // 32 K-tiles per tower
#define TAUMAX (2 * NT)             // 64 across both towers

__device__ __forceinline__ u16 f2bf(float f) {
    unsigned int u = __float_as_uint(f);
    u += 0x7FFFu + ((u >> 16) & 1u);   // round-to-nearest-even
    return (u16)(u >> 16);
}

__device__ __forceinline__ void gload_lds16(const void* g, void* l) {
    __builtin_amdgcn_global_load_lds(
        (const __attribute__((address_space(1))) void*)g,
        (__attribute__((address_space(3))) void*)l, 16, 0, 0);
}

// ---------------- Kernel 1: fused prep (unchanged; ~<85 us, not the lever yet) -
__global__ __launch_bounds__(256) void prep_kernel(
    const float* __restrict__ u, const float* __restrict__ v,
    const float* __restrict__ lnu_w, const float* __restrict__ lnu_b,
    const float* __restrict__ lnv_w, const float* __restrict__ lnv_b,
    const float* __restrict__ Wu, const float* __restrict__ Wv,
    u16* __restrict__ Au, u16* __restrict__ Av,
    u16* __restrict__ WtU, u16* __restrict__ WtV,
    float* __restrict__ out)
{
    __shared__ u16 tile[64][66];   // WT staging; stride 66 u16 -> 2-way banks (free)

    if (blockIdx.x < NROWS / 256)
        out[(blockIdx.x << 8) | threadIdx.x] = 0.f;   // folded memset

    if (blockIdx.x < LN_BLOCKS) {
        const int wave = threadIdx.x >> 6;
        const int lane = threadIdx.x & 63;
        const int r = blockIdx.x * 4 + wave;          // 0 .. 2*NROWS-1
        const bool isv = r >= NROWS;
        const int row = isv ? (r - NROWS) : r;
        const float* __restrict__ src = (isv ? v : u) + (size_t)row * DIM;
        const float* __restrict__ gw = isv ? lnv_w : lnu_w;
        const float* __restrict__ gb = isv ? lnv_b : lnu_b;
        u16* __restrict__ dst = (isv ? Av : Au) + (size_t)row * DIM;

        float4 x[8];
        #pragma unroll
        for (int i = 0; i < 8; ++i)
            x[i] = *(const float4*)(src + i * 256 + lane * 4);

        float s = 0.f, s2 = 0.f;
        #pragma unroll
        for (int i = 0; i < 8; ++i) {
            s  += (x[i].x + x[i].y) + (x[i].z + x[i].w);
            s2 += x[i].x*x[i].x + x[i].y*x[i].y + x[i].z*x[i].z + x[i].w*x[i].w;
        }
        #pragma unroll
        for (int m = 1; m < 64; m <<= 1) {
            s  += __shfl_xor(s, m);
            s2 += __shfl_xor(s2, m);
        }
        const float mu = s * (1.0f / DIM);
        const float rstd = rsqrtf(s2 * (1.0f / DIM) - mu * mu + LN_EPS);

        #pragma unroll
        for (int i = 0; i < 8; ++i) {
            const float4 w4 = *(const float4*)(gw + i * 256 + lane * 4);
            const float4 b4 = *(const float4*)(gb + i * 256 + lane * 4);
            union { u16 us[4]; uint2 v2; } pk;
            pk.us[0] = f2bf((x[i].x - mu) * rstd * w4.x + b4.x);
            pk.us[1] = f2bf((x[i].y - mu) * rstd * w4.y + b4.y);
            pk.us[2] = f2bf((x[i].z - mu) * rstd * w4.z + b4.z);
            pk.us[3] = f2bf((x[i].w - mu) * rstd * w4.w + b4.w);
            *(uint2*)(dst + i * 256 + lane * 4) = pk.v2;
        }
    } else {
        const int b = blockIdx.x - LN_BLOCKS;          // 0..2047
        const int tower = b >> 10;
        const int t6 = b & 1023;
        const int n0 = (t6 & 31) * 64;
        const int k0 = (t6 >> 5) * 64;
        const float* __restrict__ src = tower ? Wv : Wu;
        u16* __restrict__ dst = tower ? WtV : WtU;
        const int c  = threadIdx.x & 15;
        const int rq = threadIdx.x >> 4;

        #pragma unroll
        for (int i = 0; i < 4; ++i) {
            const int k = rq + 16 * i;
            const float4 w = *(const float4*)(src + (size_t)(k0 + k) * DIM + n0 + c * 4);
            union { u16 us[4]; uint2 v2; } pk;
            pk.us[0] = f2bf(w.x); pk.us[1] = f2bf(w.y);
            pk.us[2] = f2bf(w.z); pk.us[3] = f2bf(w.w);
            *(uint2*)&tile[k][c * 4] = pk.v2;
        }
        __syncthreads();
        #pragma unroll
        for (int i = 0; i < 4; ++i) {
            const int n = rq + 16 * i;
            union { u16 us[4]; uint2 v2; } pk;
            #pragma unroll
            for (int j = 0; j < 4; ++j) pk.us[j] = tile[c * 4 + j][n];
            *(uint2*)(dst + (size_t)(n0 + n) * DIM + k0 + c * 4) = pk.v2;
        }
    }
}

// ---------------- Kernel 2: m201-style 8-phase dual GEMM + bias + LeakyReLU + dot
// Per phase: {6 ds_read_b128 (1 k-step: 4 A + 2 B frags) || 2 gload_lds ||
// s_barrier || lgkmcnt(0) || setprio(1) 8 INDEPENDENT MFMA setprio(0) || s_barrier}.
// 8 phases / iteration = 2 K-tiles. Stage slots (WAR-safe, derived):
//   P0/P1: B(tau+1) -> smB[1]   (readers of smB[1] = prev iter, done)
//   P2/P3: A(tau+2) -> smA[a2]  (occupant tau-1, reads done prev P7)
//   P4/P5: B(tau+2) -> smB[0]   (occupant tau, reads done at P3 barrier)
//   P6/P7: A(tau+3) -> smA[a0]  (occupant tau, reads done at P3 barrier)
// A gets 5-6 phases issue->use slack (L3 latency), B 3-4 (L2-hot panel).
// Tile-boundary waits: vmcnt(4) after P3 and P7 (= the 4 A-loads issued after
// the last required load). Tail (i==31): vmcnt(0) at P3, none at P7.
// LDS swizzle (verified 0-conflict R0/R3, same formula): slot s of row r holds
// colblock s ^ (r&7) ^ ((r>>3)&7); staging source colblock = (lane&7)^(lane>>3)^wave.
// C/D layout (m74/m101): col = lane&31, row = (reg&3) + 8*(reg>>2) + 4*(lane>>5).
// launch_bounds (512,2): pins VGPR cap at 256 (acc 128 + hu_pk 64 + frags ~24).
__global__ __launch_bounds__(512, 2) void fused_gemm_dot(
    const u16* __restrict__ Au, const u16* __restrict__ Av,
    const u16* __restrict__ WtU, const u16* __restrict__ WtV,
    const float* __restrict__ b_u, const float* __restrict__ b_v,
    float* __restrict__ out)
{
    __shared__ __align__(16) u16 smA[3][BM * BK];   // 96 KiB (3-buf: deep A prefetch)
    __shared__ __align__(16) u16 smB[2][BN * BK];   // 64 KiB  -> 160 KiB total

    const int tid   = threadIdx.x;
    const int wave  = tid >> 6;        // 0..7
    const int lane  = tid & 63;
    const int l31   = lane & 31;       // frag row (A) / col (B,C)
    const int khalf = lane >> 5;       // which 8-wide k-half the lane holds
    const int wr    = wave >> 2;       // wave row (0..1), 128 rows each
    const int wc    = wave & 3;        // wave col (0..3), 64 cols each
    const int srow  = lane >> 3;
    const int gsw   = ((lane & 7) ^ srow ^ wave) * 8;  // source swizzle (u16)

    const int bid = blockIdx.x;        // 256 blocks = 1/CU exactly
    const int bn  = bid & 7;           // XCD id: same-bn blocks share one L2 (B panel)
    const int bm  = bid >> 3;
    const size_t arow0 = (size_t)bm * BM;
    const size_t ncol0 = (size_t)bn * BN;

// stage A half h (rows h*128..+127) of tile T into smA[buf]: 2 gloads/thread
#define STAGE_A(T, buf, h) do {                                                    \
        const u16* as_ = (((T) >= NT) ? Av : Au) + arow0 * DIM                     \
                         + (size_t)((T) & (NT - 1)) * BK;                          \
        _Pragma("unroll")                                                          \
        for (int i2_ = 0; i2_ < 2; ++i2_) {                                        \
            const int rg_ = (h) * 128 + i2_ * 64 + wave * 8;                       \
            gload_lds16(as_ + (size_t)(rg_ + srow) * DIM + gsw,                    \
                        &smA[buf][rg_ * BK]);                                      \
        }                                                                          \
    } while (0)

#define STAGE_B(T, h) do {                                                         \
        const u16* bs_ = (((T) >= NT) ? WtV : WtU) + ncol0 * DIM                   \
                         + (size_t)((T) & (NT - 1)) * BK;                          \
        _Pragma("unroll")                                                          \
        for (int i2_ = 0; i2_ < 2; ++i2_) {                                        \
            const int rg_ = (h) * 128 + i2_ * 64 + wave * 8;                       \
            gload_lds16(bs_ + (size_t)(rg_ + srow) * DIM + gsw,                    \
                        &smB[(T) & 1][rg_ * BK]);                                  \
        }                                                                          \
    } while (0)

// one phase: 6 ds_read + stage + barrier + lgkm0 + 8 independent MFMA
#define PHASE(AB, BB, KS, STAGE_STMT) do {                                         \
        const u16* sa_ = &smA[AB][0];                                              \
        const u16* sb_ = &smB[BB][0];                                              \
        const int cb_ = (KS) * 2 + khalf;                                          \
        short8 af_[4], bf_[2];                                                     \
        _Pragma("unroll")                                                          \
        for (int mi_ = 0; mi_ < 4; ++mi_) {                                        \
            const int row_ = wr * 128 + mi_ * 32 + l31;                            \
            const int sl_ = cb_ ^ (row_ & 7) ^ ((row_ >> 3) & 7);                  \
            af_[mi_] = *(const short8*)(sa_ + row_ * BK + sl_ * 8);                \
        }                                                                          \
        _Pragma("unroll")                                                          \
        for (int ni_ = 0; ni_ < 2; ++ni_) {                                        \
            const int row_ = wc * 64 + ni_ * 32 + l31;                             \
            const int sl_ = cb_ ^ (row_ & 7) ^ ((row_ >> 3) & 7);                  \
            bf_[ni_] = *(const short8*)(sb_ + row_ * BK + sl_ * 8);                \
        }                                                                          \
        STAGE_STMT;                                                                \
        __builtin_amdgcn_s_barrier();                                              \
        asm volatile("s_waitcnt lgkmcnt(0)" ::: "memory");                         \
        __builtin_amdgcn_s_setprio(1);                                             \
        _Pragma("unroll")                                                          \
        for (int mi_ = 0; mi_ < 4; ++mi_)                                          \
            _Pragma("unroll")                                                      \
            for (int ni_ = 0; ni_ < 2; ++ni_)                                      \
                acc[mi_][ni_] = __builtin_amdgcn_mfma_f32_32x32x16_bf16(           \
                    af_[mi_], bf_[ni_], acc[mi_][ni_], 0, 0, 0);                   \
        __builtin_amdgcn_s_setprio(0);                                             \
    } while (0)

    f32x16 acc[4][2];
    unsigned int hu_pk[4][2][8];   // tower-u activations, packed bf16 pairs

    #pragma unroll
    for (int mi = 0; mi < 4; ++mi)
        #pragma unroll
        for (int ni = 0; ni < 2; ++ni)
            #pragma unroll
            for (int r = 0; r < 16; ++r)
                acc[mi][ni][r] = 0.f;

    // prologue: tile0 complete (8 loads) + tile1.A (4) -> matches steady P7 state
    STAGE_A(0, 0, 0); STAGE_A(0, 0, 1);
    STAGE_B(0, 0);    STAGE_B(0, 1);
    STAGE_A(1, 1, 0); STAGE_A(1, 1, 1);
    asm volatile("s_waitcnt vmcnt(4)" ::: "memory");
    __builtin_amdgcn_s_barrier();
    asm volatile("" ::: "memory");

    int a0 = 0;   // smA buffer of tile tau; rotates +2 mod 3 per iteration
    #pragma unroll 1
    for (int i = 0; i < NT; ++i) {
        const int tau = 2 * i;
        const int a1 = (a0 + 1 < 3) ? a0 + 1 : a0 - 2;
        const int a2 = (a0 + 2 < 3) ? a0 + 2 : a0 - 1;

        PHASE(a0, 0, 0, { STAGE_B(tau + 1, 0); });
        __builtin_amdgcn_s_barrier();
        PHASE(a0, 0, 1, { STAGE_B(tau + 1, 1); });
        __builtin_amdgcn_s_barrier();
        PHASE(a0, 0, 2, { if (i < NT - 1) STAGE_A(tau + 2, a2, 0); });
        __builtin_amdgcn_s_barrier();
        PHASE(a0, 0, 3, { if (i < NT - 1) STAGE_A(tau + 2, a2, 1); });
        if (i < NT - 1) asm volatile("s_waitcnt vmcnt(4)" ::: "memory");
        else            asm volatile("s_waitcnt vmcnt(0)" ::: "memory");
        __builtin_amdgcn_s_barrier();
        asm volatile("" ::: "memory");

        PHASE(a1, 1, 0, { if (i < NT - 1) STAGE_B(tau + 2, 0); });
        __builtin_amdgcn_s_barrier();
        PHASE(a1, 1, 1, { if (i < NT - 1) STAGE_B(tau + 2, 1); });
        __builtin_amdgcn_s_barrier();
        PHASE(a1, 1, 2, { if (i < NT - 1) STAGE_A(tau + 3, a0, 0); });
        __builtin_amdgcn_s_barrier();
        PHASE(a1, 1, 3, { if (i < NT - 1) STAGE_A(tau + 3, a0, 1); });
        if (i < NT - 1) asm volatile("s_waitcnt vmcnt(4)" ::: "memory");
        __builtin_amdgcn_s_barrier();
        asm volatile("" ::: "memory");

        a0 = a2;

        if (i == 15) {
            // tower-u epilogue: bias + LeakyReLU, pack to bf16, reset acc
            #pragma unroll
            for (int ni = 0; ni < 2; ++ni) {
                const float bias = b_u[ncol0 + wc * 64 + ni * 32 + l31];
                #pragma unroll
                for (int mi = 0; mi < 4; ++mi) {
                    #pragma unroll
                    for (int p = 0; p < 8; ++p) {
                        float h0 = acc[mi][ni][p * 2] + bias;
                        float h1 = acc[mi][ni][p * 2 + 1] + bias;
                        h0 = h0 >= 0.f ? h0 : SLOPE * h0;
                        h1 = h1 >= 0.f ? h1 : SLOPE * h1;
                        hu_pk[mi][ni][p] = (unsigned)f2bf(h0) | ((unsigned)f2bf(h1) << 16);
                    }
                    #pragma unroll
                    for (int r = 0; r < 16; ++r) acc[mi][ni][r] = 0.f;
                }
            }
        }
    }

    // final epilogue: hv = leaky(acc_v + b_v); prod = hu*hv; reduce over cols
    // (lanes 0..31 hold all 32 cols of a row); atomicAdd per row.
    #pragma unroll
    for (int mi = 0; mi < 4; ++mi) {
        #pragma unroll
        for (int rg = 0; rg < 4; ++rg) {
            float rsum[4] = {0.f, 0.f, 0.f, 0.f};
            #pragma unroll
            for (int ni = 0; ni < 2; ++ni) {
                const float bias = b_v[ncol0 + wc * 64 + ni * 32 + l31];
                #pragma unroll
                for (int r = 0; r < 4; ++r) {
                    const int reg = rg * 4 + r;
                    float hv = acc[mi][ni][reg] + bias;
                    hv = hv >= 0.f ? hv : SLOPE * hv;
                    const unsigned pk = hu_pk[mi][ni][reg >> 1];
                    const unsigned bits = (reg & 1) ? (pk & 0xFFFF0000u) : (pk << 16);
                    rsum[r] += __uint_as_float(bits) * hv;
                }
            }
            #pragma unroll
            for (int r = 0; r < 4; ++r) {
                const int reg = rg * 4 + r;
                float vsum = rsum[r];
                vsum += __shfl_xor(vsum, 1);
                vsum += __shfl_xor(vsum, 2);
                vsum += __shfl_xor(vsum, 4);
                vsum += __shfl_xor(vsum, 8);
                vsum += __shfl_xor(vsum, 16);
                if (l31 == 0) {
                    const int row = (int)arow0 + wr * 128 + mi * 32
                                  + (reg & 3) + 8 * (reg >> 2) + 4 * khalf;
                    atomicAdd(out + row, vsum);
                }
            }
        }
    }
#undef STAGE_A
#undef STAGE_B
#undef PHASE
}

extern "C" void kernel_launch(void* const* d_in, const int* in_sizes, int n_in,
                              void* d_out, int out_size, void* d_ws, size_t ws_size,
                              hipStream_t stream)
{
    const float* u     = (const float*)d_in[0];
    const float* v     = (const float*)d_in[1];
    const float* lnu_w = (const float*)d_in[2];
    const float* lnu_b = (const float*)d_in[3];
    const float* lnv_w = (const float*)d_in[4];
    const float* lnv_b = (const float*)d_in[5];
    const float* W_u   = (const float*)d_in[6];
    const float* b_u   = (const float*)d_in[7];
    const float* W_v   = (const float*)d_in[8];
    const float* b_v   = (const float*)d_in[9];
    float* out = (float*)d_out;

    char* ws = (char*)d_ws;
    u16* Au  = (u16*)(ws);                                              // 33.5 MB
    u16* Av  = (u16*)(ws + (size_t)NROWS * DIM * 2);                    // 33.5 MB
    u16* WtU = (u16*)(ws + (size_t)NROWS * DIM * 4);                    //  8.4 MB
    u16* WtV = (u16*)(ws + (size_t)NROWS * DIM * 4 + (size_t)DIM * DIM * 2); // 8.4 MB

    prep_kernel<<<LN_BLOCKS + WT_BLOCKS, 256, 0, stream>>>(
        u, v, lnu_w, lnu_b, lnv_w, lnv_b, W_u, W_v, Au, Av, WtU, WtV, out);
    fused_gemm_dot<<<dim3((NROWS / BM) * (DIM / BN)), 512, 0, stream>>>(
        Au, Av, WtU, WtV, b_u, b_v, out);
}

// Round 5
// 371.292 us; speedup vs baseline: 1.0009x; 1.0009x over previous
//
#include <hip/hip_runtime.h>

typedef unsigned short u16;
typedef __attribute__((ext_vector_type(8))) short short8;
typedef __attribute__((ext_vector_type(16))) float f32x16;

#define DIM 2048
#define NROWS 8192
#define SLOPE 0.001f
#define LN_EPS 1e-5f

#define LN_BLOCKS 4096              // 16384 rows, 4 rows (waves) per block
#define WT_BLOCKS 2048              // 2 towers * (2048/64)^2 tiles

// GEMM geometry (m201-faithful): 256x256 C tile, 512 thr = 8 waves (2x4),
// 128x64 per wave (acc[4][2] of 32x32), BK=64. LDS: A 3-buf + B 2-buf = 160 KiB.
#define BM 256
#define BN 256
#define BK 64
#define NT (DIM / BK)               // 32 K-tiles per tower
#define TAUMAX (2 * NT)             // 64 across both towers

__device__ __forceinline__ u16 f2bf(float f) {
    unsigned int u = __float_as_uint(f);
    u += 0x7FFFu + ((u >> 16) & 1u);   // round-to-nearest-even
    return (u16)(u >> 16);
}

__device__ __forceinline__ void gload_lds16(const void* g, void* l) {
    __builtin_amdgcn_global_load_lds(
        (const __attribute__((address_space(1))) void*)g,
        (__attribute__((address_space(3))) void*)l, 16, 0, 0);
}

// ---------------- Kernel 1: fused prep (unchanged) ----------------------------
__global__ __launch_bounds__(256) void prep_kernel(
    const float* __restrict__ u, const float* __restrict__ v,
    const float* __restrict__ lnu_w, const float* __restrict__ lnu_b,
    const float* __restrict__ lnv_w, const float* __restrict__ lnv_b,
    const float* __restrict__ Wu, const float* __restrict__ Wv,
    u16* __restrict__ Au, u16* __restrict__ Av,
    u16* __restrict__ WtU, u16* __restrict__ WtV,
    float* __restrict__ out)
{
    __shared__ u16 tile[64][66];   // WT staging; stride 66 u16 -> 2-way banks (free)

    if (blockIdx.x < NROWS / 256)
        out[(blockIdx.x << 8) | threadIdx.x] = 0.f;   // folded memset

    if (blockIdx.x < LN_BLOCKS) {
        const int wave = threadIdx.x >> 6;
        const int lane = threadIdx.x & 63;
        const int r = blockIdx.x * 4 + wave;          // 0 .. 2*NROWS-1
        const bool isv = r >= NROWS;
        const int row = isv ? (r - NROWS) : r;
        const float* __restrict__ src = (isv ? v : u) + (size_t)row * DIM;
        const float* __restrict__ gw = isv ? lnv_w : lnu_w;
        const float* __restrict__ gb = isv ? lnv_b : lnu_b;
        u16* __restrict__ dst = (isv ? Av : Au) + (size_t)row * DIM;

        float4 x[8];
        #pragma unroll
        for (int i = 0; i < 8; ++i)
            x[i] = *(const float4*)(src + i * 256 + lane * 4);

        float s = 0.f, s2 = 0.f;
        #pragma unroll
        for (int i = 0; i < 8; ++i) {
            s  += (x[i].x + x[i].y) + (x[i].z + x[i].w);
            s2 += x[i].x*x[i].x + x[i].y*x[i].y + x[i].z*x[i].z + x[i].w*x[i].w;
        }
        #pragma unroll
        for (int m = 1; m < 64; m <<= 1) {
            s  += __shfl_xor(s, m);
            s2 += __shfl_xor(s2, m);
        }
        const float mu = s * (1.0f / DIM);
        const float rstd = rsqrtf(s2 * (1.0f / DIM) - mu * mu + LN_EPS);

        #pragma unroll
        for (int i = 0; i < 8; ++i) {
            const float4 w4 = *(const float4*)(gw + i * 256 + lane * 4);
            const float4 b4 = *(const float4*)(gb + i * 256 + lane * 4);
            union { u16 us[4]; uint2 v2; } pk;
            pk.us[0] = f2bf((x[i].x - mu) * rstd * w4.x + b4.x);
            pk.us[1] = f2bf((x[i].y - mu) * rstd * w4.y + b4.y);
            pk.us[2] = f2bf((x[i].z - mu) * rstd * w4.z + b4.z);
            pk.us[3] = f2bf((x[i].w - mu) * rstd * w4.w + b4.w);
            *(uint2*)(dst + i * 256 + lane * 4) = pk.v2;
        }
    } else {
        const int b = blockIdx.x - LN_BLOCKS;          // 0..2047
        const int tower = b >> 10;
        const int t6 = b & 1023;
        const int n0 = (t6 & 31) * 64;
        const int k0 = (t6 >> 5) * 64;
        const float* __restrict__ src = tower ? Wv : Wu;
        u16* __restrict__ dst = tower ? WtV : WtU;
        const int c  = threadIdx.x & 15;
        const int rq = threadIdx.x >> 4;

        #pragma unroll
        for (int i = 0; i < 4; ++i) {
            const int k = rq + 16 * i;
            const float4 w = *(const float4*)(src + (size_t)(k0 + k) * DIM + n0 + c * 4);
            union { u16 us[4]; uint2 v2; } pk;
            pk.us[0] = f2bf(w.x); pk.us[1] = f2bf(w.y);
            pk.us[2] = f2bf(w.z); pk.us[3] = f2bf(w.w);
            *(uint2*)&tile[k][c * 4] = pk.v2;
        }
        __syncthreads();
        #pragma unroll
        for (int i = 0; i < 4; ++i) {
            const int n = rq + 16 * i;
            union { u16 us[4]; uint2 v2; } pk;
            #pragma unroll
            for (int j = 0; j < 4; ++j) pk.us[j] = tile[c * 4 + j][n];
            *(uint2*)(dst + (size_t)(n0 + n) * DIM + k0 + c * 4) = pk.v2;
        }
    }
}

// ---------------- Kernel 2: m201-style 8-phase dual GEMM + bias + LeakyReLU + dot
// IDENTICAL to R4 except __launch_bounds__(512) -- NO min-blocks arg.
// R4 lesson (repeat of R0's "(256,3)" incident): on this toolchain the 2nd
// launch_bounds arg acts as CUDA min-BLOCKS/CU; (512,2) -> 4 waves/SIMD ->
// 128-VGPR hard cap -> hu_pk/acc spilled to scratch (WRITE 4->13.8 MB,
// FETCH 131->275 MB, MfmaUtil 29%). LDS=160K already limits to 1 block/CU
// (2 waves/SIMD, 256-VGPR cap) -- the clamp bought nothing and cost spill.
// Per phase: {6 ds_read_b128 (1 k-step: 4 A + 2 B frags) || 2 gload_lds ||
// s_barrier || lgkmcnt(0) || setprio(1) 8 INDEPENDENT MFMA setprio(0) || s_barrier}.
// 8 phases / iteration = 2 K-tiles. Stage slots (WAR-safe, derived):
//   P0/P1: B(tau+1) -> smB[1]   (readers of smB[1] = prev iter, done)
//   P2/P3: A(tau+2) -> smA[a2]  (occupant tau-1, reads done prev P7)
//   P4/P5: B(tau+2) -> smB[0]   (occupant tau, reads done at P3 barrier)
//   P6/P7: A(tau+3) -> smA[a0]  (occupant tau, reads done at P3 barrier)
// Tile-boundary waits: vmcnt(4) after P3 and P7. Tail (i==31): vmcnt(0) at P3.
// LDS swizzle (verified 0-conflict): slot s of row r holds colblock
// s ^ (r&7) ^ ((r>>3)&7); staging source colblock = (lane&7)^(lane>>3)^wave.
// C/D layout (m74/m101): col = lane&31, row = (reg&3) + 8*(reg>>2) + 4*(lane>>5).
__global__ __launch_bounds__(512) void fused_gemm_dot(
    const u16* __restrict__ Au, const u16* __restrict__ Av,
    const u16* __restrict__ WtU, const u16* __restrict__ WtV,
    const float* __restrict__ b_u, const float* __restrict__ b_v,
    float* __restrict__ out)
{
    __shared__ __align__(16) u16 smA[3][BM * BK];   // 96 KiB (3-buf: deep A prefetch)
    __shared__ __align__(16) u16 smB[2][BN * BK];   // 64 KiB  -> 160 KiB total

    const int tid   = threadIdx.x;
    const int wave  = tid >> 6;        // 0..7
    const int lane  = tid & 63;
    const int l31   = lane & 31;       // frag row (A) / col (B,C)
    const int khalf = lane >> 5;       // which 8-wide k-half the lane holds
    const int wr    = wave >> 2;       // wave row (0..1), 128 rows each
    const int wc    = wave & 3;        // wave col (0..3), 64 cols each
    const int srow  = lane >> 3;
    const int gsw   = ((lane & 7) ^ srow ^ wave) * 8;  // source swizzle (u16)

    const int bid = blockIdx.x;        // 256 blocks = 1/CU exactly
    const int bn  = bid & 7;           // XCD id: same-bn blocks share one L2 (B panel)
    const int bm  = bid >> 3;
    const size_t arow0 = (size_t)bm * BM;
    const size_t ncol0 = (size_t)bn * BN;

// stage A half h (rows h*128..+127) of tile T into smA[buf]: 2 gloads/thread
#define STAGE_A(T, buf, h) do {                                                    \
        const u16* as_ = (((T) >= NT) ? Av : Au) + arow0 * DIM                     \
                         + (size_t)((T) & (NT - 1)) * BK;                          \
        _Pragma("unroll")                                                          \
        for (int i2_ = 0; i2_ < 2; ++i2_) {                                        \
            const int rg_ = (h) * 128 + i2_ * 64 + wave * 8;                       \
            gload_lds16(as_ + (size_t)(rg_ + srow) * DIM + gsw,                    \
                        &smA[buf][rg_ * BK]);                                      \
        }                                                                          \
    } while (0)

#define STAGE_B(T, h) do {                                                         \
        const u16* bs_ = (((T) >= NT) ? WtV : WtU) + ncol0 * DIM                   \
                         + (size_t)((T) & (NT - 1)) * BK;                          \
        _Pragma("unroll")                                                          \
        for (int i2_ = 0; i2_ < 2; ++i2_) {                                        \
            const int rg_ = (h) * 128 + i2_ * 64 + wave * 8;                       \
            gload_lds16(bs_ + (size_t)(rg_ + srow) * DIM + gsw,                    \
                        &smB[(T) & 1][rg_ * BK]);                                  \
        }                                                                          \
    } while (0)

// one phase: 6 ds_read + stage + barrier + lgkm0 + 8 independent MFMA
#define PHASE(AB, BB, KS, STAGE_STMT) do {                                         \
        const u16* sa_ = &smA[AB][0];                                              \
        const u16* sb_ = &smB[BB][0];                                              \
        const int cb_ = (KS) * 2 + khalf;                                          \
        short8 af_[4], bf_[2];                                                     \
        _Pragma("unroll")                                                          \
        for (int mi_ = 0; mi_ < 4; ++mi_) {                                        \
            const int row_ = wr * 128 + mi_ * 32 + l31;                            \
            const int sl_ = cb_ ^ (row_ & 7) ^ ((row_ >> 3) & 7);                  \
            af_[mi_] = *(const short8*)(sa_ + row_ * BK + sl_ * 8);                \
        }                                                                          \
        _Pragma("unroll")                                                          \
        for (int ni_ = 0; ni_ < 2; ++ni_) {                                        \
            const int row_ = wc * 64 + ni_ * 32 + l31;                             \
            const int sl_ = cb_ ^ (row_ & 7) ^ ((row_ >> 3) & 7);                  \
            bf_[ni_] = *(const short8*)(sb_ + row_ * BK + sl_ * 8);                \
        }                                                                          \
        STAGE_STMT;                                                                \
        __builtin_amdgcn_s_barrier();                                              \
        asm volatile("s_waitcnt lgkmcnt(0)" ::: "memory");                         \
        __builtin_amdgcn_s_setprio(1);                                             \
        _Pragma("unroll")                                                          \
        for (int mi_ = 0; mi_ < 4; ++mi_)                                          \
            _Pragma("unroll")                                                      \
            for (int ni_ = 0; ni_ < 2; ++ni_)                                      \
                acc[mi_][ni_] = __builtin_amdgcn_mfma_f32_32x32x16_bf16(           \
                    af_[mi_], bf_[ni_], acc[mi_][ni_], 0, 0, 0);                   \
        __builtin_amdgcn_s_setprio(0);                                             \
    } while (0)

    f32x16 acc[4][2];
    unsigned int hu_pk[4][2][8];   // tower-u activations, packed bf16 pairs

    #pragma unroll
    for (int mi = 0; mi < 4; ++mi)
        #pragma unroll
        for (int ni = 0; ni < 2; ++ni)
            #pragma unroll
            for (int r = 0; r < 16; ++r)
                acc[mi][ni][r] = 0.f;

    // prologue: tile0 complete (8 loads) + tile1.A (4) -> matches steady P7 state
    STAGE_A(0, 0, 0); STAGE_A(0, 0, 1);
    STAGE_B(0, 0);    STAGE_B(0, 1);
    STAGE_A(1, 1, 0); STAGE_A(1, 1, 1);
    asm volatile("s_waitcnt vmcnt(4)" ::: "memory");
    __builtin_amdgcn_s_barrier();
    asm volatile("" ::: "memory");

    int a0 = 0;   // smA buffer of tile tau; rotates +2 mod 3 per iteration
    #pragma unroll 1
    for (int i = 0; i < NT; ++i) {
        const int tau = 2 * i;
        const int a1 = (a0 + 1 < 3) ? a0 + 1 : a0 - 2;
        const int a2 = (a0 + 2 < 3) ? a0 + 2 : a0 - 1;

        PHASE(a0, 0, 0, { STAGE_B(tau + 1, 0); });
        __builtin_amdgcn_s_barrier();
        PHASE(a0, 0, 1, { STAGE_B(tau + 1, 1); });
        __builtin_amdgcn_s_barrier();
        PHASE(a0, 0, 2, { if (i < NT - 1) STAGE_A(tau + 2, a2, 0); });
        __builtin_amdgcn_s_barrier();
        PHASE(a0, 0, 3, { if (i < NT - 1) STAGE_A(tau + 2, a2, 1); });
        if (i < NT - 1) asm volatile("s_waitcnt vmcnt(4)" ::: "memory");
        else            asm volatile("s_waitcnt vmcnt(0)" ::: "memory");
        __builtin_amdgcn_s_barrier();
        asm volatile("" ::: "memory");

        PHASE(a1, 1, 0, { if (i < NT - 1) STAGE_B(tau + 2, 0); });
        __builtin_amdgcn_s_barrier();
        PHASE(a1, 1, 1, { if (i < NT - 1) STAGE_B(tau + 2, 1); });
        __builtin_amdgcn_s_barrier();
        PHASE(a1, 1, 2, { if (i < NT - 1) STAGE_A(tau + 3, a0, 0); });
        __builtin_amdgcn_s_barrier();
        PHASE(a1, 1, 3, { if (i < NT - 1) STAGE_A(tau + 3, a0, 1); });
        if (i < NT - 1) asm volatile("s_waitcnt vmcnt(4)" ::: "memory");
        __builtin_amdgcn_s_barrier();
        asm volatile("" ::: "memory");

        a0 = a2;

        if (i == 15) {
            // tower-u epilogue: bias + LeakyReLU, pack to bf16, reset acc
            #pragma unroll
            for (int ni = 0; ni < 2; ++ni) {
                const float bias = b_u[ncol0 + wc * 64 + ni * 32 + l31];
                #pragma unroll
                for (int mi = 0; mi < 4; ++mi) {
                    #pragma unroll
                    for (int p = 0; p < 8; ++p) {
                        float h0 = acc[mi][ni][p * 2] + bias;
                        float h1 = acc[mi][ni][p * 2 + 1] + bias;
                        h0 = h0 >= 0.f ? h0 : SLOPE * h0;
                        h1 = h1 >= 0.f ? h1 : SLOPE * h1;
                        hu_pk[mi][ni][p] = (unsigned)f2bf(h0) | ((unsigned)f2bf(h1) << 16);
                    }
                    #pragma unroll
                    for (int r = 0; r < 16; ++r) acc[mi][ni][r] = 0.f;
                }
            }
        }
    }

    // final epilogue: hv = leaky(acc_v + b_v); prod = hu*hv; reduce over cols
    // (lanes 0..31 hold all 32 cols of a row); atomicAdd per row.
    #pragma unroll
    for (int mi = 0; mi < 4; ++mi) {
        #pragma unroll
        for (int rg = 0; rg < 4; ++rg) {
            float rsum[4] = {0.f, 0.f, 0.f, 0.f};
            #pragma unroll
            for (int ni = 0; ni < 2; ++ni) {
                const float bias = b_v[ncol0 + wc * 64 + ni * 32 + l31];
                #pragma unroll
                for (int r = 0; r < 4; ++r) {
                    const int reg = rg * 4 + r;
                    float hv = acc[mi][ni][reg] + bias;
                    hv = hv >= 0.f ? hv : SLOPE * hv;
                    const unsigned pk = hu_pk[mi][ni][reg >> 1];
                    const unsigned bits = (reg & 1) ? (pk & 0xFFFF0000u) : (pk << 16);
                    rsum[r] += __uint_as_float(bits) * hv;
                }
            }
            #pragma unroll
            for (int r = 0; r < 4; ++r) {
                const int reg = rg * 4 + r;
                float vsum = rsum[r];
                vsum += __shfl_xor(vsum, 1);
                vsum += __shfl_xor(vsum, 2);
                vsum += __shfl_xor(vsum, 4);
                vsum += __shfl_xor(vsum, 8);
                vsum += __shfl_xor(vsum, 16);
                if (l31 == 0) {
                    const int row = (int)arow0 + wr * 128 + mi * 32
                                  + (reg & 3) + 8 * (reg >> 2) + 4 * khalf;
                    atomicAdd(out + row, vsum);
                }
            }
        }
    }
#undef STAGE_A
#undef STAGE_B
#undef PHASE
}

extern "C" void kernel_launch(void* const* d_in, const int* in_sizes, int n_in,
                              void* d_out, int out_size, void* d_ws, size_t ws_size,
                              hipStream_t stream)
{
    const float* u     = (const float*)d_in[0];
    const float* v     = (const float*)d_in[1];
    const float* lnu_w = (const float*)d_in[2];
    const float* lnu_b = (const float*)d_in[3];
    const float* lnv_w = (const float*)d_in[4];
    const float* lnv_b = (const float*)d_in[5];
    const float* W_u   = (const float*)d_in[6];
    const float* b_u   = (const float*)d_in[7];
    const float* W_v   = (const float*)d_in[8];
    const float* b_v   = (const float*)d_in[9];
    float* out = (float*)d_out;

    char* ws = (char*)d_ws;
    u16* Au  = (u16*)(ws);                                              // 33.5 MB
    u16* Av  = (u16*)(ws + (size_t)NROWS * DIM * 2);                    // 33.5 MB
    u16* WtU = (u16*)(ws + (size_t)NROWS * DIM * 4);                    //  8.4 MB
    u16* WtV = (u16*)(ws + (size_t)NROWS * DIM * 4 + (size_t)DIM * DIM * 2); // 8.4 MB

    prep_kernel<<<LN_BLOCKS + WT_BLOCKS, 256, 0, stream>>>(
        u, v, lnu_w, lnu_b, lnv_w, lnv_b, W_u, W_v, Au, Av, WtU, WtV, out);
    fused_gemm_dot<<<dim3((NROWS / BM) * (DIM / BN)), 512, 0, stream>>>(
        Au, Av, WtU, WtV, b_u, b_v, out);
}

// Round 6
// 352.538 us; speedup vs baseline: 1.0542x; 1.0532x over previous
//
#include <hip/hip_runtime.h>

typedef unsigned short u16;
typedef __attribute__((ext_vector_type(8))) short short8;
typedef __attribute__((ext_vector_type(16))) float f32x16;

#define DIM 2048
#define NROWS 8192
#define SLOPE 0.001f
#define LN_EPS 1e-5f

#define LN_BLOCKS 4096              // 16384 rows, 4 rows (waves) per block
#define WT_BLOCKS 2048              // 2 towers * (2048/64)^2 tiles

// GEMM geometry (m201-faithful): 256x256 C tile, 512 thr = 8 waves (2x4),
// 128x64 per wave (acc[4][2] of 32x32), BK=64. LDS: A 3-buf + B 2-buf = 160 KiB.
#define BM 256
#define BN 256
#define BK 64
#define NT (DIM / BK)               // 32 K-tiles per tower
#define TAUMAX (2 * NT)             // 64 across both towers

__device__ __forceinline__ u16 f2bf(float f) {
    unsigned int u = __float_as_uint(f);
    u += 0x7FFFu + ((u >> 16) & 1u);   // round-to-nearest-even
    return (u16)(u >> 16);
}

__device__ __forceinline__ void gload_lds16(const void* g, void* l) {
    __builtin_amdgcn_global_load_lds(
        (const __attribute__((address_space(1))) void*)g,
        (__attribute__((address_space(3))) void*)l, 16, 0, 0);
}

// ---------------- Kernel 1: fused prep (unchanged) ----------------------------
__global__ __launch_bounds__(256) void prep_kernel(
    const float* __restrict__ u, const float* __restrict__ v,
    const float* __restrict__ lnu_w, const float* __restrict__ lnu_b,
    const float* __restrict__ lnv_w, const float* __restrict__ lnv_b,
    const float* __restrict__ Wu, const float* __restrict__ Wv,
    u16* __restrict__ Au, u16* __restrict__ Av,
    u16* __restrict__ WtU, u16* __restrict__ WtV,
    float* __restrict__ out)
{
    __shared__ u16 tile[64][66];   // WT staging; stride 66 u16 -> 2-way banks (free)

    if (blockIdx.x < NROWS / 256)
        out[(blockIdx.x << 8) | threadIdx.x] = 0.f;   // folded memset

    if (blockIdx.x < LN_BLOCKS) {
        const int wave = threadIdx.x >> 6;
        const int lane = threadIdx.x & 63;
        const int r = blockIdx.x * 4 + wave;          // 0 .. 2*NROWS-1
        const bool isv = r >= NROWS;
        const int row = isv ? (r - NROWS) : r;
        const float* __restrict__ src = (isv ? v : u) + (size_t)row * DIM;
        const float* __restrict__ gw = isv ? lnv_w : lnu_w;
        const float* __restrict__ gb = isv ? lnv_b : lnu_b;
        u16* __restrict__ dst = (isv ? Av : Au) + (size_t)row * DIM;

        float4 x[8];
        #pragma unroll
        for (int i = 0; i < 8; ++i)
            x[i] = *(const float4*)(src + i * 256 + lane * 4);

        float s = 0.f, s2 = 0.f;
        #pragma unroll
        for (int i = 0; i < 8; ++i) {
            s  += (x[i].x + x[i].y) + (x[i].z + x[i].w);
            s2 += x[i].x*x[i].x + x[i].y*x[i].y + x[i].z*x[i].z + x[i].w*x[i].w;
        }
        #pragma unroll
        for (int m = 1; m < 64; m <<= 1) {
            s  += __shfl_xor(s, m);
            s2 += __shfl_xor(s2, m);
        }
        const float mu = s * (1.0f / DIM);
        const float rstd = rsqrtf(s2 * (1.0f / DIM) - mu * mu + LN_EPS);

        #pragma unroll
        for (int i = 0; i < 8; ++i) {
            const float4 w4 = *(const float4*)(gw + i * 256 + lane * 4);
            const float4 b4 = *(const float4*)(gb + i * 256 + lane * 4);
            union { u16 us[4]; uint2 v2; } pk;
            pk.us[0] = f2bf((x[i].x - mu) * rstd * w4.x + b4.x);
            pk.us[1] = f2bf((x[i].y - mu) * rstd * w4.y + b4.y);
            pk.us[2] = f2bf((x[i].z - mu) * rstd * w4.z + b4.z);
            pk.us[3] = f2bf((x[i].w - mu) * rstd * w4.w + b4.w);
            *(uint2*)(dst + i * 256 + lane * 4) = pk.v2;
        }
    } else {
        const int b = blockIdx.x - LN_BLOCKS;          // 0..2047
        const int tower = b >> 10;
        const int t6 = b & 1023;
        const int n0 = (t6 & 31) * 64;
        const int k0 = (t6 >> 5) * 64;
        const float* __restrict__ src = tower ? Wv : Wu;
        u16* __restrict__ dst = tower ? WtV : WtU;
        const int c  = threadIdx.x & 15;
        const int rq = threadIdx.x >> 4;

        #pragma unroll
        for (int i = 0; i < 4; ++i) {
            const int k = rq + 16 * i;
            const float4 w = *(const float4*)(src + (size_t)(k0 + k) * DIM + n0 + c * 4);
            union { u16 us[4]; uint2 v2; } pk;
            pk.us[0] = f2bf(w.x); pk.us[1] = f2bf(w.y);
            pk.us[2] = f2bf(w.z); pk.us[3] = f2bf(w.w);
            *(uint2*)&tile[k][c * 4] = pk.v2;
        }
        __syncthreads();
        #pragma unroll
        for (int i = 0; i < 4; ++i) {
            const int n = rq + 16 * i;
            union { u16 us[4]; uint2 v2; } pk;
            #pragma unroll
            for (int j = 0; j < 4; ++j) pk.us[j] = tile[c * 4 + j][n];
            *(uint2*)(dst + (size_t)(n0 + n) * DIM + k0 + c * 4) = pk.v2;
        }
    }
}

// ---------------- Kernel 2: m201-style 8-phase dual GEMM + bias + LeakyReLU + dot
// R5 LESSON (register budget, structural): at 2 waves/SIMD the unified
// VGPR+AGPR budget is 256/wave. acc[4][2] = 128 AGPR leaves exactly 128 arch
// VGPRs; a persistent hu_pk[64] cannot fit -> compiler spilled (~19 regs,
// FETCH +144 MB, MfmaUtil 29%) REGARDLESS of launch_bounds. Fix: hu round-trips
// through global Hu (33.5 MB, ~11 us HBM) -> no persistent hu registers.
// Schedule (verified correct R4/R5): per phase {6 ds_read_b128 (4 A + 2 B
// frags) || 2 gload_lds || s_barrier || lgkmcnt(0) || setprio(1) 8 independent
// MFMA setprio(0) || s_barrier}. 8 phases / iteration = 2 K-tiles:
//   P0/P1: B(tau+1) -> smB[1]; P2/P3: A(tau+2) -> smA[a2];
//   P4/P5: B(tau+2) -> smB[0]; P6/P7: A(tau+3) -> smA[a0].
// vmcnt(4) after P3 and P7 (counted, never 0 mid-loop; tail i==31: vmcnt(0)).
// Hu stores (i==15) sit oldest in the VMEM queue; i==16's first vmcnt(4)
// retires them -> one small bubble, correct counting preserved.
// LDS swizzle (verified 0-conflict): slot s of row r holds colblock
// s ^ (r&7) ^ ((r>>3)&7); staging source colblock = (lane&7)^(lane>>3)^wave.
// C/D layout (m74/m101): col = lane&31, row = (reg&3) + 8*(reg>>2) + 4*(lane>>5).
__global__ __launch_bounds__(512) void fused_gemm_dot(
    const u16* __restrict__ Au, const u16* __restrict__ Av,
    const u16* __restrict__ WtU, const u16* __restrict__ WtV,
    const float* __restrict__ b_u, const float* __restrict__ b_v,
    uint4* __restrict__ Hu, float* __restrict__ out)
{
    __shared__ __align__(16) u16 smA[3][BM * BK];   // 96 KiB (3-buf: deep A prefetch)
    __shared__ __align__(16) u16 smB[2][BN * BK];   // 64 KiB  -> 160 KiB total

    const int tid   = threadIdx.x;
    const int wave  = tid >> 6;        // 0..7
    const int lane  = tid & 63;
    const int l31   = lane & 31;       // frag row (A) / col (B,C)
    const int khalf = lane >> 5;       // which 8-wide k-half the lane holds
    const int wr    = wave >> 2;       // wave row (0..1), 128 rows each
    const int wc    = wave & 3;        // wave col (0..3), 64 cols each
    const int srow  = lane >> 3;
    const int gsw   = ((lane & 7) ^ srow ^ wave) * 8;  // source swizzle (u16)

    const int bid = blockIdx.x;        // 256 blocks = 1/CU exactly
    const int bn  = bid & 7;           // XCD id: same-bn blocks share one L2 (B panel)
    const int bm  = bid >> 3;
    const size_t arow0 = (size_t)bm * BM;
    const size_t ncol0 = (size_t)bn * BN;

// stage A half h (rows h*128..+127) of tile T into smA[buf]: 2 gloads/thread
#define STAGE_A(T, buf, h) do {                                                    \
        const u16* as_ = (((T) >= NT) ? Av : Au) + arow0 * DIM                     \
                         + (size_t)((T) & (NT - 1)) * BK;                          \
        _Pragma("unroll")                                                          \
        for (int i2_ = 0; i2_ < 2; ++i2_) {                                        \
            const int rg_ = (h) * 128 + i2_ * 64 + wave * 8;                       \
            gload_lds16(as_ + (size_t)(rg_ + srow) * DIM + gsw,                    \
                        &smA[buf][rg_ * BK]);                                      \
        }                                                                          \
    } while (0)

#define STAGE_B(T, h) do {                                                         \
        const u16* bs_ = (((T) >= NT) ? WtV : WtU) + ncol0 * DIM                   \
                         + (size_t)((T) & (NT - 1)) * BK;                          \
        _Pragma("unroll")                                                          \
        for (int i2_ = 0; i2_ < 2; ++i2_) {                                        \
            const int rg_ = (h) * 128 + i2_ * 64 + wave * 8;                       \
            gload_lds16(bs_ + (size_t)(rg_ + srow) * DIM + gsw,                    \
                        &smB[(T) & 1][rg_ * BK]);                                  \
        }                                                                          \
    } while (0)

// one phase: 6 ds_read + stage + barrier + lgkm0 + 8 independent MFMA
#define PHASE(AB, BB, KS, STAGE_STMT) do {                                         \
        const u16* sa_ = &smA[AB][0];                                              \
        const u16* sb_ = &smB[BB][0];                                              \
        const int cb_ = (KS) * 2 + khalf;                                          \
        short8 af_[4], bf_[2];                                                     \
        _Pragma("unroll")                                                          \
        for (int mi_ = 0; mi_ < 4; ++mi_) {                                        \
            const int row_ = wr * 128 + mi_ * 32 + l31;                            \
            const int sl_ = cb_ ^ (row_ & 7) ^ ((row_ >> 3) & 7);                  \
            af_[mi_] = *(const short8*)(sa_ + row_ * BK + sl_ * 8);                \
        }                                                                          \
        _Pragma("unroll")                                                          \
        for (int ni_ = 0; ni_ < 2; ++ni_) {                                        \
            const int row_ = wc * 64 + ni_ * 32 + l31;                             \
            const int sl_ = cb_ ^ (row_ & 7) ^ ((row_ >> 3) & 7);                  \
            bf_[ni_] = *(const short8*)(sb_ + row_ * BK + sl_ * 8);                \
        }                                                                          \
        STAGE_STMT;                                                                \
        __builtin_amdgcn_s_barrier();                                              \
        asm volatile("s_waitcnt lgkmcnt(0)" ::: "memory");                         \
        __builtin_amdgcn_s_setprio(1);                                             \
        _Pragma("unroll")                                                          \
        for (int mi_ = 0; mi_ < 4; ++mi_)                                          \
            _Pragma("unroll")                                                      \
            for (int ni_ = 0; ni_ < 2; ++ni_)                                      \
                acc[mi_][ni_] = __builtin_amdgcn_mfma_f32_32x32x16_bf16(           \
                    af_[mi_], bf_[ni_], acc[mi_][ni_], 0, 0, 0);                   \
        __builtin_amdgcn_s_setprio(0);                                             \
    } while (0)

    f32x16 acc[4][2];

    #pragma unroll
    for (int mi = 0; mi < 4; ++mi)
        #pragma unroll
        for (int ni = 0; ni < 2; ++ni)
            #pragma unroll
            for (int r = 0; r < 16; ++r)
                acc[mi][ni][r] = 0.f;

    // prologue: tile0 complete (8 loads) + tile1.A (4) -> matches steady P7 state
    STAGE_A(0, 0, 0); STAGE_A(0, 0, 1);
    STAGE_B(0, 0);    STAGE_B(0, 1);
    STAGE_A(1, 1, 0); STAGE_A(1, 1, 1);
    asm volatile("s_waitcnt vmcnt(4)" ::: "memory");
    __builtin_amdgcn_s_barrier();
    asm volatile("" ::: "memory");

    int a0 = 0;   // smA buffer of tile tau; rotates +2 mod 3 per iteration
    #pragma unroll 1
    for (int i = 0; i < NT; ++i) {
        const int tau = 2 * i;
        const int a1 = (a0 + 1 < 3) ? a0 + 1 : a0 - 2;
        const int a2 = (a0 + 2 < 3) ? a0 + 2 : a0 - 1;

        PHASE(a0, 0, 0, { STAGE_B(tau + 1, 0); });
        __builtin_amdgcn_s_barrier();
        PHASE(a0, 0, 1, { STAGE_B(tau + 1, 1); });
        __builtin_amdgcn_s_barrier();
        PHASE(a0, 0, 2, { if (i < NT - 1) STAGE_A(tau + 2, a2, 0); });
        __builtin_amdgcn_s_barrier();
        PHASE(a0, 0, 3, { if (i < NT - 1) STAGE_A(tau + 2, a2, 1); });
        if (i < NT - 1) asm volatile("s_waitcnt vmcnt(4)" ::: "memory");
        else            asm volatile("s_waitcnt vmcnt(0)" ::: "memory");
        __builtin_amdgcn_s_barrier();
        asm volatile("" ::: "memory");

        PHASE(a1, 1, 0, { if (i < NT - 1) STAGE_B(tau + 2, 0); });
        __builtin_amdgcn_s_barrier();
        PHASE(a1, 1, 1, { if (i < NT - 1) STAGE_B(tau + 2, 1); });
        __builtin_amdgcn_s_barrier();
        PHASE(a1, 1, 2, { if (i < NT - 1) STAGE_A(tau + 3, a0, 0); });
        __builtin_amdgcn_s_barrier();
        PHASE(a1, 1, 3, { if (i < NT - 1) STAGE_A(tau + 3, a0, 1); });
        if (i < NT - 1) asm volatile("s_waitcnt vmcnt(4)" ::: "memory");
        __builtin_amdgcn_s_barrier();
        asm volatile("" ::: "memory");

        a0 = a2;

        if (i == 15) {
            // tower-u epilogue: bias + LeakyReLU, pack bf16, SPILL TO GLOBAL
            // (coalesced dwordx4: for fixed q, consecutive tid -> consecutive
            // uint4), then reset acc. No persistent hu registers survive.
            #pragma unroll
            for (int mi = 0; mi < 4; ++mi) {
                #pragma unroll
                for (int ni = 0; ni < 2; ++ni) {
                    const float bias = b_u[ncol0 + wc * 64 + ni * 32 + l31];
                    unsigned pk[8];
                    #pragma unroll
                    for (int p = 0; p < 8; ++p) {
                        float h0 = acc[mi][ni][p * 2] + bias;
                        float h1 = acc[mi][ni][p * 2 + 1] + bias;
                        h0 = h0 >= 0.f ? h0 : SLOPE * h0;
                        h1 = h1 >= 0.f ? h1 : SLOPE * h1;
                        pk[p] = (unsigned)f2bf(h0) | ((unsigned)f2bf(h1) << 16);
                    }
                    Hu[((size_t)bid * 16 + mi * 4 + ni * 2 + 0) * 512 + tid] =
                        make_uint4(pk[0], pk[1], pk[2], pk[3]);
                    Hu[((size_t)bid * 16 + mi * 4 + ni * 2 + 1) * 512 + tid] =
                        make_uint4(pk[4], pk[5], pk[6], pk[7]);
                }
                #pragma unroll
                for (int ni = 0; ni < 2; ++ni)
                    #pragma unroll
                    for (int r = 0; r < 16; ++r) acc[mi][ni][r] = 0.f;
            }
        }
    }

    // final epilogue: reload hu, hv = leaky(acc_v + b_v); prod = hu*hv; reduce
    // over cols (lanes 0..31 hold all 32 cols of a row); atomicAdd per row.
    // Hu stores (i==15) were forced complete by i==16's vmcnt(4) -> reload safe.
    asm volatile("s_waitcnt vmcnt(0)" ::: "memory");
    #pragma unroll
    for (int mi = 0; mi < 4; ++mi) {
        union { uint4 v4[4]; unsigned w[16]; } hu;
        #pragma unroll
        for (int j = 0; j < 4; ++j)
            hu.v4[j] = Hu[((size_t)bid * 16 + mi * 4 + j) * 512 + tid];
        #pragma unroll
        for (int rg = 0; rg < 4; ++rg) {
            float rsum[4] = {0.f, 0.f, 0.f, 0.f};
            #pragma unroll
            for (int ni = 0; ni < 2; ++ni) {
                const float bias = b_v[ncol0 + wc * 64 + ni * 32 + l31];
                #pragma unroll
                for (int r = 0; r < 4; ++r) {
                    const int reg = rg * 4 + r;
                    float hv = acc[mi][ni][reg] + bias;
                    hv = hv >= 0.f ? hv : SLOPE * hv;
                    const unsigned pk = hu.w[ni * 8 + (reg >> 1)];
                    const unsigned bits = (reg & 1) ? (pk & 0xFFFF0000u) : (pk << 16);
                    rsum[r] += __uint_as_float(bits) * hv;
                }
            }
            #pragma unroll
            for (int r = 0; r < 4; ++r) {
                const int reg = rg * 4 + r;
                float vsum = rsum[r];
                vsum += __shfl_xor(vsum, 1);
                vsum += __shfl_xor(vsum, 2);
                vsum += __shfl_xor(vsum, 4);
                vsum += __shfl_xor(vsum, 8);
                vsum += __shfl_xor(vsum, 16);
                if (l31 == 0) {
                    const int row = (int)arow0 + wr * 128 + mi * 32
                                  + (reg & 3) + 8 * (reg >> 2) + 4 * khalf;
                    atomicAdd(out + row, vsum);
                }
            }
        }
    }
#undef STAGE_A
#undef STAGE_B
#undef PHASE
}

extern "C" void kernel_launch(void* const* d_in, const int* in_sizes, int n_in,
                              void* d_out, int out_size, void* d_ws, size_t ws_size,
                              hipStream_t stream)
{
    const float* u     = (const float*)d_in[0];
    const float* v     = (const float*)d_in[1];
    const float* lnu_w = (const float*)d_in[2];
    const float* lnu_b = (const float*)d_in[3];
    const float* lnv_w = (const float*)d_in[4];
    const float* lnv_b = (const float*)d_in[5];
    const float* W_u   = (const float*)d_in[6];
    const float* b_u   = (const float*)d_in[7];
    const float* W_v   = (const float*)d_in[8];
    const float* b_v   = (const float*)d_in[9];
    float* out = (float*)d_out;

    char* ws = (char*)d_ws;
    u16*  Au  = (u16*)(ws);                                                  // 33.5 MB
    u16*  Av  = (u16*)(ws + (size_t)NROWS * DIM * 2);                        // 33.5 MB
    u16*  WtU = (u16*)(ws + (size_t)NROWS * DIM * 4);                        //  8.4 MB
    u16*  WtV = (u16*)(ws + (size_t)NROWS * DIM * 4 + (size_t)DIM * DIM * 2);//  8.4 MB
    uint4* Hu = (uint4*)(ws + (size_t)NROWS * DIM * 4 + (size_t)DIM * DIM * 4); // 33.5 MB (hu tile spill)

    prep_kernel<<<LN_BLOCKS + WT_BLOCKS, 256, 0, stream>>>(
        u, v, lnu_w, lnu_b, lnv_w, lnv_b, W_u, W_v, Au, Av, WtU, WtV, out);
    fused_gemm_dot<<<dim3((NROWS / BM) * (DIM / BN)), 512, 0, stream>>>(
        Au, Av, WtU, WtV, b_u, b_v, Hu, out);
}